// Round 3
// baseline (769.992 us; speedup 1.0000x reference)
//
#include <hip/hip_runtime.h>
#include <hip/hip_bf16.h>

// ArcFace head, single fused kernel:
//   128x128 tile, BK=64, 512 threads (8 waves: 4m x 2n of 32x64).
//   Register-staged fp32 -> bf16 with double-buffered LDS, 1 barrier/K-step:
//     issue loads(k+1) -> MFMA(k) -> convert+ds_write(k+1) -> barrier.
//   Per-row norms accumulated from the fp32 values during staging.
//   XOR-swizzled LDS (elem (4sc)^((row&7)<<3)) -> conflict-free reads+writes.
//   XCD-swizzled grid, m fastest -> W n-tile fetched from HBM once.

typedef __attribute__((ext_vector_type(8))) short short8;
typedef __attribute__((ext_vector_type(4))) float f32x4;

#define TH_CONST  (-0.8775825618903728f)   // cos(pi - 0.5)
#define MM_CONST  (0.23971276930210156f)   // sin(pi - 0.5) * 0.5
#define M_MARGIN  0.5f
#define S_SCALE   64.0f
#define KD 512   // feature dim (fixed by problem)

__device__ __forceinline__ unsigned short bfc(float x) {
    // RNE fp32->bf16 via HW cvt (compiler pairs these into v_cvt_pk_bf16_f32)
    union { __hip_bfloat16 h; unsigned short u; } cv;
    cv.h = __float2bfloat16(x);
    return cv.u;
}

__global__ __launch_bounds__(512, 4)
void arcface_fused2(const float* __restrict__ F,      // [512][512]
                    const int*   __restrict__ labels, // [512]
                    const float* __restrict__ W,      // [C][512]
                    float*       __restrict__ Out,    // [512][C]
                    const int C, const int GM)
{
    __shared__ __align__(16) unsigned short As[2][128 * 64];  // 2 x 16 KB
    __shared__ __align__(16) unsigned short Bs[2][128 * 64];  // 2 x 16 KB
    __shared__ float nF[128];
    __shared__ float nW[128];
    __shared__ int   Ls[128];

    // Bijective XCD swizzle (m204); m fastest inside each XCD chunk so the
    // GM blocks sharing a W-tile land on the same XCD/L2.
    const int nwg = gridDim.x;
    const int bid = blockIdx.x;
    const int q   = nwg >> 3, rr = nwg & 7;
    const int xcd = bid & 7,  seq = bid >> 3;
    const int wg  = (xcd < rr ? xcd * (q + 1) : rr * (q + 1) + (xcd - rr) * q) + seq;
    const int mt  = wg % GM;
    const int nt  = wg / GM;
    const int m_base = mt * 128;
    const int n_base = nt * 128;

    const int t    = threadIdx.x;          // 0..511
    const int wave = t >> 6;               // 0..7
    const int lane = t & 63;
    const int wm   = (wave & 3) * 32;      // 4 m-waves
    const int wn   = (wave >> 2) * 64;     // 2 n-waves
    const int quad = lane >> 4;
    const int lcol = lane & 15;

    if (t < 128) Ls[t] = labels[m_base + t];

    // ---- staging geometry: thread t = (row-group sg, k-chunk sc) ----
    // Per K-step each thread loads ONE float4 for 4 rows {sg+32i} of A and B.
    // One load instruction = 4 consecutive rows x 256 B contiguous (coalesced).
    const int sg = t >> 4;                 // 0..31
    const int sc = t & 15;                 // k-chunk (4 floats)

    unsigned int aOff[4], bOff[4];
    int wof[4];
    #pragma unroll
    for (int i = 0; i < 4; ++i) {
        const int rA = sg + 32 * i;        // tile-local row 0..127
        aOff[i] = (unsigned int)((m_base + rA) * KD + 4 * sc) * 4u;
        int rB = n_base + rA;
        if (rB >= C) rB = C - 1;           // clamp; stores are guarded
        bOff[i] = (unsigned int)rB * (KD * 4u) + 16u * sc;
        // element offset in LDS row: XOR-swizzle kills read & write conflicts
        wof[i]  = rA * 64 + ((4 * sc) ^ ((rA & 7) << 3));
    }

    float sA[4] = {0.f, 0.f, 0.f, 0.f};
    float sB[4] = {0.f, 0.f, 0.f, 0.f};
    float4 va[4], vb[4];

    const char* Fc = (const char*)F;
    const char* Wc = (const char*)W;

    f32x4 acc[2][4];
    #pragma unroll
    for (int i = 0; i < 2; ++i)
        #pragma unroll
        for (int j = 0; j < 4; ++j)
            acc[i][j] = (f32x4){0.f, 0.f, 0.f, 0.f};

    auto load_tile = [&](int kt) {
        const unsigned int ko = (unsigned int)kt * 256u;   // 64 floats
        #pragma unroll
        for (int i = 0; i < 4; ++i) {
            va[i] = *(const float4*)(Fc + (aOff[i] + ko));
            vb[i] = *(const float4*)(Wc + (bOff[i] + ko));
        }
    };

    auto convert_write = [&](int nb) {
        unsigned short* ab = As[nb];
        unsigned short* bb = Bs[nb];
        #pragma unroll
        for (int i = 0; i < 4; ++i) {
            float4 v = va[i];
            sA[i] += v.x * v.x + v.y * v.y + v.z * v.z + v.w * v.w;
            ushort4 p;
            p.x = bfc(v.x); p.y = bfc(v.y); p.z = bfc(v.z); p.w = bfc(v.w);
            *(ushort4*)&ab[wof[i]] = p;

            float4 u = vb[i];
            sB[i] += u.x * u.x + u.y * u.y + u.z * u.z + u.w * u.w;
            ushort4 r;
            r.x = bfc(u.x); r.y = bfc(u.y); r.z = bfc(u.z); r.w = bfc(u.w);
            *(ushort4*)&bb[wof[i]] = r;
        }
    };

    auto mfma_tile = [&](int cb) {
        const unsigned short* ab = As[cb];
        const unsigned short* bb = Bs[cb];
        const int sw = (lcol & 7) << 3;    // row&7 == lcol&7 (wm, i*16 are x8)
        #pragma unroll
        for (int h = 0; h < 2; ++h) {
            const int co = (quad * 8 + 32 * h) ^ sw;
            short8 af[2], bf_[4];
            #pragma unroll
            for (int i = 0; i < 2; ++i)
                af[i] = *(const short8*)&ab[(wm + i * 16 + lcol) * 64 + co];
            #pragma unroll
            for (int j = 0; j < 4; ++j)
                bf_[j] = *(const short8*)&bb[(wn + j * 16 + lcol) * 64 + co];
            #pragma unroll
            for (int i = 0; i < 2; ++i)
                #pragma unroll
                for (int j = 0; j < 4; ++j)
                    acc[i][j] = __builtin_amdgcn_mfma_f32_16x16x32_bf16(
                                    af[i], bf_[j], acc[i][j], 0, 0, 0);
        }
    };

    // ---- pipelined K-loop: 8 steps, 1 barrier each ----
    load_tile(0);
    convert_write(0);
    __syncthreads();

    #pragma unroll
    for (int kt = 0; kt < KD / 64; ++kt) {
        if (kt < KD / 64 - 1) load_tile(kt + 1);   // HBM latency hides under MFMA
        mfma_tile(kt & 1);
        if (kt < KD / 64 - 1) convert_write((kt + 1) & 1);
        __syncthreads();
    }

    // ---- finish norms: reduce across the 16 k-chunk lanes of each row-group ----
    #pragma unroll
    for (int i = 0; i < 4; ++i) {
        float s = sA[i];
        s += __shfl_xor(s, 1); s += __shfl_xor(s, 2);
        s += __shfl_xor(s, 4); s += __shfl_xor(s, 8);
        float w = sB[i];
        w += __shfl_xor(w, 1); w += __shfl_xor(w, 2);
        w += __shfl_xor(w, 4); w += __shfl_xor(w, 8);
        if (sc == 0) {
            nF[sg + 32 * i] = 1.0f / sqrtf(s + 1e-12f);
            nW[sg + 32 * i] = 1.0f / sqrtf(w + 1e-12f);
        }
    }
    __syncthreads();

    // ---- epilogue: C/D layout col=lane&15, row=quad*4+reg. Plain stores. ----
    #pragma unroll
    for (int i = 0; i < 2; ++i) {
        const int rl0 = wm + i * 16 + quad * 4;
        #pragma unroll
        for (int rg = 0; rg < 4; ++rg) {
            const int rl = rl0 + rg;
            const float invf = nF[rl];
            const int lbl = Ls[rl];
            float* orow = Out + (size_t)(m_base + rl) * C;
            #pragma unroll
            for (int j = 0; j < 4; ++j) {
                const int cl = wn + j * 16 + lcol;
                const int gcol = n_base + cl;
                if (gcol < C) {
                    float v = acc[i][j][rg] * invf * nW[cl];
                    v = fminf(1.0f, fmaxf(-1.0f, v));
                    if (gcol == lbl) {
                        v = (v > TH_CONST) ? cosf(acosf(v) + M_MARGIN)
                                           : (v - MM_CONST);
                    }
                    orow[gcol] = S_SCALE * v;
                }
            }
        }
    }
}

// ---------------------------------------------------------------------------
// Fallback: original verified fused kernel (only used if B % 128 != 0).
// ---------------------------------------------------------------------------
typedef __attribute__((ext_vector_type(8))) unsigned short u16x8;

__device__ __forceinline__ unsigned short f2bf(float x) {
    unsigned int u = __float_as_uint(x);
    u += 0x7fffu + ((u >> 16) & 1u);
    return (unsigned short)(u >> 16);
}

#define BM 128
#define BN 128
#define BK 32

__global__ __launch_bounds__(256, 2)
void arcface_fused_kernel(const float* __restrict__ F,
                          const int*   __restrict__ labels,
                          const float* __restrict__ W,
                          float*       __restrict__ Out,
                          const int C)
{
    __shared__ unsigned short Asf[BM][BK];
    __shared__ unsigned short Bsf[BN][BK];
    __shared__ float normF[BM];
    __shared__ float normW[BN];
    __shared__ int   Lsf[BM];

    const int t = threadIdx.x;
    const int m_base = blockIdx.x * BM;
    const int n_base = blockIdx.y * BN;

    if (t < BM) Lsf[t] = labels[m_base + t];

    const int r = t >> 1;
    const int h = t & 1;

    const int lane = t & 63;
    const int wave = t >> 6;
    const int wm = (wave >> 1) * 64;
    const int wn = (wave & 1) * 64;
    const int quad = lane >> 4;
    const int lcol = lane & 15;

    f32x4 acc[4][4];
    #pragma unroll
    for (int i = 0; i < 4; ++i)
        #pragma unroll
        for (int j = 0; j < 4; ++j)
            acc[i][j] = (f32x4){0.f, 0.f, 0.f, 0.f};

    const int cls = n_base + r;
    const bool cvalid = (cls < C);

    const float* Arow = F + (size_t)(m_base + r) * KD + h * 16;
    const float* Wrow = W + (size_t)(cvalid ? cls : 0) * KD + h * 16;

    float sF = 0.f, sW = 0.f;

    for (int kt = 0; kt < KD / BK; ++kt) {
        const float4* ap = (const float4*)(Arow + kt * BK);
        const float4* wp = (const float4*)(Wrow + kt * BK);
        float4 a0 = ap[0], a1 = ap[1], a2 = ap[2], a3 = ap[3];
        float4 w0, w1, w2, w3;
        if (cvalid) { w0 = wp[0]; w1 = wp[1]; w2 = wp[2]; w3 = wp[3]; }
        else { w0 = make_float4(0.f,0.f,0.f,0.f); w1 = w0; w2 = w0; w3 = w0; }

        sF += a0.x*a0.x + a0.y*a0.y + a0.z*a0.z + a0.w*a0.w
            + a1.x*a1.x + a1.y*a1.y + a1.z*a1.z + a1.w*a1.w
            + a2.x*a2.x + a2.y*a2.y + a2.z*a2.z + a2.w*a2.w
            + a3.x*a3.x + a3.y*a3.y + a3.z*a3.z + a3.w*a3.w;
        sW += w0.x*w0.x + w0.y*w0.y + w0.z*w0.z + w0.w*w0.w
            + w1.x*w1.x + w1.y*w1.y + w1.z*w1.z + w1.w*w1.w
            + w2.x*w2.x + w2.y*w2.y + w2.z*w2.z + w2.w*w2.w
            + w3.x*w3.x + w3.y*w3.y + w3.z*w3.z + w3.w*w3.w;

        u16x8 pa0, pa1, pb0, pb1;
        pa0[0]=f2bf(a0.x); pa0[1]=f2bf(a0.y); pa0[2]=f2bf(a0.z); pa0[3]=f2bf(a0.w);
        pa0[4]=f2bf(a1.x); pa0[5]=f2bf(a1.y); pa0[6]=f2bf(a1.z); pa0[7]=f2bf(a1.w);
        pa1[0]=f2bf(a2.x); pa1[1]=f2bf(a2.y); pa1[2]=f2bf(a2.z); pa1[3]=f2bf(a2.w);
        pa1[4]=f2bf(a3.x); pa1[5]=f2bf(a3.y); pa1[6]=f2bf(a3.z); pa1[7]=f2bf(a3.w);
        pb0[0]=f2bf(w0.x); pb0[1]=f2bf(w0.y); pb0[2]=f2bf(w0.z); pb0[3]=f2bf(w0.w);
        pb0[4]=f2bf(w1.x); pb0[5]=f2bf(w1.y); pb0[6]=f2bf(w1.z); pb0[7]=f2bf(w1.w);
        pb1[0]=f2bf(w2.x); pb1[1]=f2bf(w2.y); pb1[2]=f2bf(w2.z); pb1[3]=f2bf(w2.w);
        pb1[4]=f2bf(w3.x); pb1[5]=f2bf(w3.y); pb1[6]=f2bf(w3.z); pb1[7]=f2bf(w3.w);

        __syncthreads();
        *((u16x8*)&Asf[r][h*16])     = pa0;
        *((u16x8*)&Asf[r][h*16 + 8]) = pa1;
        *((u16x8*)&Bsf[r][h*16])     = pb0;
        *((u16x8*)&Bsf[r][h*16 + 8]) = pb1;
        __syncthreads();

        short8 af[4], bfr[4];
        #pragma unroll
        for (int i = 0; i < 4; ++i) {
            af[i]  = *(const short8*)&Asf[wm + i*16 + lcol][quad*8];
            bfr[i] = *(const short8*)&Bsf[wn + i*16 + lcol][quad*8];
        }
        #pragma unroll
        for (int i = 0; i < 4; ++i)
            #pragma unroll
            for (int j = 0; j < 4; ++j)
                acc[i][j] = __builtin_amdgcn_mfma_f32_16x16x32_bf16(
                                af[i], bfr[j], acc[i][j], 0, 0, 0);
    }

    sF += __shfl_xor(sF, 1);
    sW += __shfl_xor(sW, 1);
    if (h == 0) {
        normF[r] = 1.0f / sqrtf(sF + 1e-12f);
        normW[r] = 1.0f / sqrtf(sW + 1e-12f);
    }
    __syncthreads();

    #pragma unroll
    for (int mi = 0; mi < 4; ++mi) {
        const int rl_base = wm + mi*16 + quad*4;
        #pragma unroll
        for (int rg = 0; rg < 4; ++rg) {
            const int rl = rl_base + rg;
            const float invf = normF[rl];
            const int lbl = Lsf[rl];
            float* orow = Out + (size_t)(m_base + rl) * C;
            #pragma unroll
            for (int ni = 0; ni < 4; ++ni) {
                const int cl = wn + ni*16 + lcol;
                const int gcol = n_base + cl;
                if (gcol < C) {
                    float v = acc[mi][ni][rg] * invf * normW[cl];
                    v = fminf(1.0f, fmaxf(-1.0f, v));
                    if (gcol == lbl) {
                        v = (v > TH_CONST) ? cosf(acosf(v) + M_MARGIN)
                                           : (v - MM_CONST);
                    }
                    orow[gcol] = S_SCALE * v;
                }
            }
        }
    }
}

// ---------------------------------------------------------------------------
extern "C" void kernel_launch(void* const* d_in, const int* in_sizes, int n_in,
                              void* d_out, int out_size, void* d_ws, size_t ws_size,
                              hipStream_t stream) {
    const float* F      = (const float*)d_in[0];
    const int*   labels = (const int*)d_in[1];
    const float* W      = (const float*)d_in[2];
    float*       Out    = (float*)d_out;

    const int B = in_sizes[1];          // 512
    const int C = in_sizes[2] / KD;     // 100000

    if ((B % 128) == 0) {
        const int GM = B / 128;
        const int NT = (C + 127) / 128;
        arcface_fused2<<<GM * NT, dim3(512), 0, stream>>>(F, labels, W, Out, C, GM);
    } else {
        dim3 grid((B + BM - 1) / BM, (C + BN - 1) / BN);
        arcface_fused_kernel<<<grid, dim3(256), 0, stream>>>(F, labels, W, Out, C);
    }
}

// Round 4
// 506.338 us; speedup vs baseline: 1.5207x; 1.5207x over previous
//
#include <hip/hip_runtime.h>

// ArcFace head, two-pass:
//   pass 1: fp32 -> bf16 convert of W and F + per-row inverse L2 norms
//           (2 rows per wave-iteration, 64B/lane)
//   pass 2: bf16 MFMA GEMM, 128x128 tile, BK=64, DOUBLE-BUFFERED LDS with a
//           1-barrier counted-wait K-loop: STAGE(t+1) -> MFMA(t) -> vmcnt(0)
//           -> s_barrier. XOR-swizzled LDS (src-side pre-swizzle for
//           global_load_lds, swizzled ds_read) -> 0 bank conflicts.
//           Margin/scale epilogue with PLAIN stores (NT caused write amp).
// Falls back to the verified fused kernel if workspace is too small.

typedef __attribute__((ext_vector_type(8))) short short8;
typedef __attribute__((ext_vector_type(8))) unsigned short u16x8;
typedef __attribute__((ext_vector_type(4))) float f32x4;

#define TH_CONST  (-0.8775825618903728f)   // cos(pi - 0.5)
#define MM_CONST  (0.23971276930210156f)   // sin(pi - 0.5) * 0.5
#define M_MARGIN  0.5f
#define S_SCALE   64.0f
#define KD 512   // feature dim (fixed by problem)

__device__ __forceinline__ unsigned short f2bf(float x) {
    // round-to-nearest-even fp32 -> bf16 (finite gaussian inputs; no NaN path)
    unsigned int u = __float_as_uint(x);
    u += 0x7fffu + ((u >> 16) & 1u);
    return (unsigned short)(u >> 16);
}

// ---------------------------------------------------------------------------
// Pass 1: 2 rows per wave-iteration. 32 lanes x 16 floats = 512 = KD per row.
// ---------------------------------------------------------------------------
__global__ __launch_bounds__(256)
void convert_norm_kernel(const float* __restrict__ W,
                         const float* __restrict__ F,
                         unsigned short* __restrict__ Wb,
                         unsigned short* __restrict__ Fb,
                         float* __restrict__ invW,
                         float* __restrict__ invF,
                         const int C, const int B)
{
    const int lane = threadIdx.x & 63;
    const int half = lane >> 5;          // which row of the pair
    const int l5   = lane & 31;
    const int total  = C + B;
    const int npairs = (total + 1) >> 1;

    int pair = blockIdx.x * 4 + (threadIdx.x >> 6);
    const int stride = gridDim.x * 4;

    for (; pair < npairs; pair += stride) {
        const int row = pair * 2 + half;
        const bool valid = (row < total);
        float ss = 0.f;
        float* inv = nullptr;
        unsigned short* dst = nullptr;

        if (valid) {
            const float* src;
            if (row < C) {
                src = W + (size_t)row * KD;
                dst = Wb + (size_t)row * KD;
                inv = invW + row;
            } else {
                const int r = row - C;
                src = F + (size_t)r * KD;
                dst = Fb + (size_t)r * KD;
                inv = invF + r;
            }
            const float4* p = (const float4*)(src + l5 * 16);
            float4 v0 = p[0], v1 = p[1], v2 = p[2], v3 = p[3];

            ss = v0.x*v0.x + v0.y*v0.y + v0.z*v0.z + v0.w*v0.w
               + v1.x*v1.x + v1.y*v1.y + v1.z*v1.z + v1.w*v1.w
               + v2.x*v2.x + v2.y*v2.y + v2.z*v2.z + v2.w*v2.w
               + v3.x*v3.x + v3.y*v3.y + v3.z*v3.z + v3.w*v3.w;

            u16x8 pk0, pk1;
            pk0[0]=f2bf(v0.x); pk0[1]=f2bf(v0.y); pk0[2]=f2bf(v0.z); pk0[3]=f2bf(v0.w);
            pk0[4]=f2bf(v1.x); pk0[5]=f2bf(v1.y); pk0[6]=f2bf(v1.z); pk0[7]=f2bf(v1.w);
            pk1[0]=f2bf(v2.x); pk1[1]=f2bf(v2.y); pk1[2]=f2bf(v2.z); pk1[3]=f2bf(v2.w);
            pk1[4]=f2bf(v3.x); pk1[5]=f2bf(v3.y); pk1[6]=f2bf(v3.z); pk1[7]=f2bf(v3.w);
            *(u16x8*)(dst + l5 * 16)     = pk0;
            *(u16x8*)(dst + l5 * 16 + 8) = pk1;
        }

        // reduce within each 32-lane half (xor masks < 32 stay in-half)
        ss += __shfl_xor(ss, 1);
        ss += __shfl_xor(ss, 2);
        ss += __shfl_xor(ss, 4);
        ss += __shfl_xor(ss, 8);
        ss += __shfl_xor(ss, 16);
        if (valid && l5 == 0) *inv = 1.0f / sqrtf(ss + 1e-12f);
    }
}

// ---------------------------------------------------------------------------
// Pass 2: bf16 GEMM. Tile 128x128, BK=64, 4 waves (2x2 of 64x64).
// Double-buffered LDS; 1 barrier + counted wait per K-step.
// LDS tile rows are 128 B. Bank-conflict-free via XOR swizzle of the 16B slot
// index with (row&7): applied on the GLOBAL source address (global_load_lds
// writes linearly) and again on the ds_read address (same involution).
// ---------------------------------------------------------------------------
__device__ __forceinline__ void gload_lds_16(const void* g, void* l) {
    __builtin_amdgcn_global_load_lds(
        (const __attribute__((address_space(1))) unsigned int*)g,
        (__attribute__((address_space(3))) unsigned int*)l,
        16, 0, 0);
}

__global__ __launch_bounds__(256, 2)
void arcface_gemm_kernel(const unsigned short* __restrict__ Fb,   // [B][512] bf16
                         const unsigned short* __restrict__ Wb,   // [C][512] bf16
                         const float* __restrict__ invF,
                         const float* __restrict__ invW,
                         const int*   __restrict__ labels,
                         float*       __restrict__ Out,           // [B][C]
                         const int C, const int GM)
{
    // [2 buffers][128 rows][64 bf16] each = 16 KB -> 64 KB total (2 blocks/CU)
    __shared__ unsigned short As[2][128 * 64];
    __shared__ unsigned short Bs[2][128 * 64];
    __shared__ float nF[128];
    __shared__ float nW[128];
    __shared__ int   Ls[128];

    // Bijective XCD swizzle (m204); m fastest inside each XCD chunk.
    const int nwg = gridDim.x;
    const int bid = blockIdx.x;
    const int q   = nwg >> 3, rr = nwg & 7;
    const int xcd = bid & 7,  seq = bid >> 3;
    const int wg  = (xcd < rr ? xcd * (q + 1) : rr * (q + 1) + (xcd - rr) * q) + seq;
    const int mt  = wg % GM;
    const int nt  = wg / GM;

    const int m_base = mt * 128;
    const int n_base = nt * 128;

    const int t    = threadIdx.x;
    const int wave = t >> 6;
    const int lane = t & 63;
    const int wm   = (wave >> 1) * 64;
    const int wn   = (wave & 1) * 64;
    const int quad = lane >> 4;
    const int lcol = lane & 15;

    if (t < 128) {
        nF[t] = invF[m_base + t];
        const int c = n_base + t;
        nW[t] = (c < C) ? invW[c] : 0.f;
        Ls[t] = labels[m_base + t];
    }

    // ---- staging geometry ----
    // call c (0..3) covers tile rows c*32..c*32+31; thread t owns 16 B at
    // linear LDS offset c*4096 + t*16  ->  row = c*32 + (t>>3), slot = t&7.
    // Source column is the swizzled slot: slot' = slot ^ (row&7).
    const int rbase  = t >> 3;                                  // 0..31
    const int colSwz = (((t & 7) ^ ((t >> 3) & 7)) << 4);       // bytes

    const char* gA = (const char*)Fb + (size_t)(m_base + rbase) * (KD * 2) + colSwz;

    unsigned int offB[4];
    #pragma unroll
    for (int c = 0; c < 4; ++c) {
        int rb = n_base + c * 32 + rbase;
        if (rb >= C) rb = C - 1;           // clamp; stores are guarded
        offB[c] = (unsigned int)rb * (KD * 2) + colSwz;
    }
    const char* gWb = (const char*)Wb;

    char* lA = (char*)As + wave * 1024;    // wave-uniform; + nb*16384 + c*4096
    char* lB = (char*)Bs + wave * 1024;

    f32x4 acc[4][4];
    #pragma unroll
    for (int i = 0; i < 4; ++i)
        #pragma unroll
        for (int j = 0; j < 4; ++j)
            acc[i][j] = (f32x4){0.f, 0.f, 0.f, 0.f};

    const int sw = (lcol & 7) << 4;        // read-side swizzle (row&7 == lcol&7)

    // stage K-step kt into buffer nb (8 global_load_lds, 16 B each)
    auto stage = [&](int kt, int nb) {
        const int ko = kt * 128;           // 64 bf16 = 128 B per K-step
        const int bo = nb * 16384;
        #pragma unroll
        for (int c = 0; c < 4; ++c)
            gload_lds_16(gA + c * 32768 + ko, lA + bo + c * 4096);
        #pragma unroll
        for (int c = 0; c < 4; ++c)
            gload_lds_16(gWb + offB[c] + ko, lB + bo + c * 4096);
    };

    // ds_read + 32 MFMAs on buffer nb
    auto compute = [&](int nb) {
        const char* ab = (const char*)As + nb * 16384;
        const char* bb = (const char*)Bs + nb * 16384;
        #pragma unroll
        for (int h = 0; h < 2; ++h) {
            const int co = ((h * 64) | (quad * 16)) ^ sw;
            short8 af[4], bfr[4];
            #pragma unroll
            for (int i = 0; i < 4; ++i) {
                af[i]  = *(const short8*)(ab + (wm + i * 16 + lcol) * 128 + co);
                bfr[i] = *(const short8*)(bb + (wn + i * 16 + lcol) * 128 + co);
            }
            #pragma unroll
            for (int i = 0; i < 4; ++i)
                #pragma unroll
                for (int j = 0; j < 4; ++j)
                    acc[i][j] = __builtin_amdgcn_mfma_f32_16x16x32_bf16(
                                    af[i], bfr[j], acc[i][j], 0, 0, 0);
        }
    };

    // ---- pipelined K-loop: 1 barrier per step, counted drain AFTER compute ----
    stage(0, 0);
    asm volatile("s_waitcnt vmcnt(0)" ::: "memory");
    __builtin_amdgcn_s_barrier();

    #pragma unroll 1
    for (int kt = 0; kt < KD / 64; ++kt) {
        const int cur = kt & 1;
        if (kt < KD / 64 - 1)
            stage(kt + 1, cur ^ 1);        // issue next tile first (latency hides
        __builtin_amdgcn_sched_barrier(0); //  under this tile's ds_read+MFMA)
        compute(cur);
        asm volatile("s_waitcnt vmcnt(0)" ::: "memory");  // next tile landed
        __builtin_amdgcn_s_barrier();      // everyone done reading buf cur
    }

    // ---- epilogue: C/D layout col=lane&15, row=quad*4+reg. Plain stores. ----
    #pragma unroll
    for (int mi = 0; mi < 4; ++mi) {
        const int rl_base = wm + mi * 16 + quad * 4;
        #pragma unroll
        for (int rg = 0; rg < 4; ++rg) {
            const int rl = rl_base + rg;
            const float invf = nF[rl];
            const int lbl = Ls[rl];
            float* orow = Out + (size_t)(m_base + rl) * C;
            #pragma unroll
            for (int ni = 0; ni < 4; ++ni) {
                const int cl = wn + ni * 16 + lcol;
                const int gcol = n_base + cl;
                if (gcol < C) {
                    float v = acc[mi][ni][rg] * invf * nW[cl];
                    v = fminf(1.0f, fmaxf(-1.0f, v));
                    if (gcol == lbl) {
                        v = (v > TH_CONST) ? cosf(acosf(v) + M_MARGIN)
                                           : (v - MM_CONST);
                    }
                    orow[gcol] = S_SCALE * v;
                }
            }
        }
    }
}

// ---------------------------------------------------------------------------
// Fallback: verified fused kernel (used only if workspace too small).
// ---------------------------------------------------------------------------
#define BM 128
#define BN 128
#define BK 32

__global__ __launch_bounds__(256, 2)
void arcface_fused_kernel(const float* __restrict__ F,
                          const int*   __restrict__ labels,
                          const float* __restrict__ W,
                          float*       __restrict__ Out,
                          const int C)
{
    __shared__ unsigned short Asf[BM][BK];
    __shared__ unsigned short Bsf[BN][BK];
    __shared__ float normF[BM];
    __shared__ float normW[BN];
    __shared__ int   Lsf[BM];

    const int t = threadIdx.x;
    const int m_base = blockIdx.x * BM;
    const int n_base = blockIdx.y * BN;

    if (t < BM) Lsf[t] = labels[m_base + t];

    const int r = t >> 1;
    const int h = t & 1;

    const int lane = t & 63;
    const int wave = t >> 6;
    const int wm = (wave >> 1) * 64;
    const int wn = (wave & 1) * 64;
    const int quad = lane >> 4;
    const int lcol = lane & 15;

    f32x4 acc[4][4];
    #pragma unroll
    for (int i = 0; i < 4; ++i)
        #pragma unroll
        for (int j = 0; j < 4; ++j)
            acc[i][j] = (f32x4){0.f, 0.f, 0.f, 0.f};

    const int cls = n_base + r;
    const bool cvalid = (cls < C);

    const float* Arow = F + (size_t)(m_base + r) * KD + h * 16;
    const float* Wrow = W + (size_t)(cvalid ? cls : 0) * KD + h * 16;

    float sF = 0.f, sW = 0.f;

    for (int kt = 0; kt < KD / BK; ++kt) {
        const float4* ap = (const float4*)(Arow + kt * BK);
        const float4* wp = (const float4*)(Wrow + kt * BK);
        float4 a0 = ap[0], a1 = ap[1], a2 = ap[2], a3 = ap[3];
        float4 w0, w1, w2, w3;
        if (cvalid) { w0 = wp[0]; w1 = wp[1]; w2 = wp[2]; w3 = wp[3]; }
        else { w0 = make_float4(0.f,0.f,0.f,0.f); w1 = w0; w2 = w0; w3 = w0; }

        sF += a0.x*a0.x + a0.y*a0.y + a0.z*a0.z + a0.w*a0.w
            + a1.x*a1.x + a1.y*a1.y + a1.z*a1.z + a1.w*a1.w
            + a2.x*a2.x + a2.y*a2.y + a2.z*a2.z + a2.w*a2.w
            + a3.x*a3.x + a3.y*a3.y + a3.z*a3.z + a3.w*a3.w;
        sW += w0.x*w0.x + w0.y*w0.y + w0.z*w0.z + w0.w*w0.w
            + w1.x*w1.x + w1.y*w1.y + w1.z*w1.z + w1.w*w1.w
            + w2.x*w2.x + w2.y*w2.y + w2.z*w2.z + w2.w*w2.w
            + w3.x*w3.x + w3.y*w3.y + w3.z*w3.z + w3.w*w3.w;

        u16x8 pa0, pa1, pb0, pb1;
        pa0[0]=f2bf(a0.x); pa0[1]=f2bf(a0.y); pa0[2]=f2bf(a0.z); pa0[3]=f2bf(a0.w);
        pa0[4]=f2bf(a1.x); pa0[5]=f2bf(a1.y); pa0[6]=f2bf(a1.z); pa0[7]=f2bf(a1.w);
        pa1[0]=f2bf(a2.x); pa1[1]=f2bf(a2.y); pa1[2]=f2bf(a2.z); pa1[3]=f2bf(a2.w);
        pa1[4]=f2bf(a3.x); pa1[5]=f2bf(a3.y); pa1[6]=f2bf(a3.z); pa1[7]=f2bf(a3.w);
        pb0[0]=f2bf(w0.x); pb0[1]=f2bf(w0.y); pb0[2]=f2bf(w0.z); pb0[3]=f2bf(w0.w);
        pb0[4]=f2bf(w1.x); pb0[5]=f2bf(w1.y); pb0[6]=f2bf(w1.z); pb0[7]=f2bf(w1.w);
        pb1[0]=f2bf(w2.x); pb1[1]=f2bf(w2.y); pb1[2]=f2bf(w2.z); pb1[3]=f2bf(w2.w);
        pb1[4]=f2bf(w3.x); pb1[5]=f2bf(w3.y); pb1[6]=f2bf(w3.z); pb1[7]=f2bf(w3.w);

        __syncthreads();
        *((u16x8*)&Asf[r][h*16])     = pa0;
        *((u16x8*)&Asf[r][h*16 + 8]) = pa1;
        *((u16x8*)&Bsf[r][h*16])     = pb0;
        *((u16x8*)&Bsf[r][h*16 + 8]) = pb1;
        __syncthreads();

        short8 af[4], bfr[4];
        #pragma unroll
        for (int i = 0; i < 4; ++i) {
            af[i]  = *(const short8*)&Asf[wm + i*16 + lcol][quad*8];
            bfr[i] = *(const short8*)&Bsf[wn + i*16 + lcol][quad*8];
        }
        #pragma unroll
        for (int i = 0; i < 4; ++i)
            #pragma unroll
            for (int j = 0; j < 4; ++j)
                acc[i][j] = __builtin_amdgcn_mfma_f32_16x16x32_bf16(
                                af[i], bfr[j], acc[i][j], 0, 0, 0);
    }

    sF += __shfl_xor(sF, 1);
    sW += __shfl_xor(sW, 1);
    if (h == 0) {
        normF[r] = 1.0f / sqrtf(sF + 1e-12f);
        normW[r] = 1.0f / sqrtf(sW + 1e-12f);
    }
    __syncthreads();

    #pragma unroll
    for (int mi = 0; mi < 4; ++mi) {
        const int rl_base = wm + mi*16 + quad*4;
        #pragma unroll
        for (int rg = 0; rg < 4; ++rg) {
            const int rl = rl_base + rg;
            const float invf = normF[rl];
            const int lbl = Lsf[rl];
            float* orow = Out + (size_t)(m_base + rl) * C;
            #pragma unroll
            for (int ni = 0; ni < 4; ++ni) {
                const int cl = wn + ni*16 + lcol;
                const int gcol = n_base + cl;
                if (gcol < C) {
                    float v = acc[mi][ni][rg] * invf * normW[cl];
                    v = fminf(1.0f, fmaxf(-1.0f, v));
                    if (gcol == lbl) {
                        v = (v > TH_CONST) ? cosf(acosf(v) + M_MARGIN)
                                           : (v - MM_CONST);
                    }
                    orow[gcol] = S_SCALE * v;
                }
            }
        }
    }
}

// ---------------------------------------------------------------------------
extern "C" void kernel_launch(void* const* d_in, const int* in_sizes, int n_in,
                              void* d_out, int out_size, void* d_ws, size_t ws_size,
                              hipStream_t stream) {
    const float* F      = (const float*)d_in[0];
    const int*   labels = (const int*)d_in[1];
    const float* W      = (const float*)d_in[2];
    float*       Out    = (float*)d_out;

    const int B = in_sizes[1];          // 512
    const int C = in_sizes[2] / KD;     // 100000

    // workspace layout (256B-aligned chunks)
    const size_t a = 255;
    size_t offWb = 0;
    size_t szWb  = (size_t)C * KD * sizeof(unsigned short);
    size_t offFb = (offWb + szWb + a) & ~a;
    size_t szFb  = (size_t)B * KD * sizeof(unsigned short);
    size_t offIW = (offFb + szFb + a) & ~a;
    size_t szIW  = (size_t)C * sizeof(float);
    size_t offIF = (offIW + szIW + a) & ~a;
    size_t szIF  = (size_t)B * sizeof(float);
    size_t need  = offIF + szIF;

    if (d_ws != nullptr && ws_size >= need && (B % 128) == 0) {
        unsigned short* Wb   = (unsigned short*)((char*)d_ws + offWb);
        unsigned short* Fb   = (unsigned short*)((char*)d_ws + offFb);
        float*          invW = (float*)((char*)d_ws + offIW);
        float*          invF = (float*)((char*)d_ws + offIF);

        convert_norm_kernel<<<2048, 256, 0, stream>>>(W, F, Wb, Fb, invW, invF, C, B);

        const int GM = B / 128;
        const int NT = (C + 127) / 128;
        arcface_gemm_kernel<<<GM * NT, 256, 0, stream>>>(Fb, Wb, invF, invW,
                                                         labels, Out, C, GM);
    } else {
        dim3 grid((B + BM - 1) / BM, (C + BN - 1) / BN);
        arcface_fused_kernel<<<grid, dim3(256), 0, stream>>>(F, labels, W, Out, C);
    }
}